// Round 11
// baseline (295.887 us; speedup 1.0000x reference)
//
#include <hip/hip_runtime.h>
#include <math.h>

#define N_NODES 650
#define DIM     512
#define E_RAW   150000
#define E_TOT   150650
#define WK      672              // padded row length for dense attention matrix (672 = 42*16)

// =============== feature GEMM (split-K z=8) + fused logits, atomic accumulation ===============
// h[r,c] += (A @ B)[r,c] partial over k in [z*64,(z+1)*64); als/ald get partial dots.
// a_mode 1: rows<400 from A (x_s), >=400 from Axt (x_t).
// a_mode 2: A = raw agg output; apply relu(raw*inv_rs + bias_prev) while staging.
__global__ __launch_bounds__(256)
void k_feat(const float* __restrict__ A, const float* __restrict__ Axt,
            const float* __restrict__ B,
            const float* __restrict__ asrc, const float* __restrict__ adst,
            const float* __restrict__ rsp, const float* __restrict__ bp,
            float* __restrict__ h, float* __restrict__ als, float* __restrict__ ald,
            int a_mode) {
    __shared__ float Ast[16][68];   // transposed A tile (stride 68)
    __shared__ float Bs[16][64];
    int t = threadIdx.x;
    int tx4 = (t & 15) * 4, ty4 = (t >> 4) * 4;
    int row0 = blockIdx.y * 64, col0 = blockIdx.x * 64;
    int kbase = blockIdx.z * 64;
    int ar = t >> 2, ak = (t & 3) * 4;     // A staging: 64 rows x 16 k
    int bk = t >> 4, bn = (t & 15) * 4;    // B staging: 16 k x 64 cols
    float acc[4][4] = {};

    for (int kb = kbase; kb < kbase + 64; kb += 16) {
        {
            int gr = row0 + ar;
            float4 v = make_float4(0.f, 0.f, 0.f, 0.f);
            if (gr < N_NODES) {
                if (a_mode == 1) {
                    const float* rowp = (gr < 400) ? A + (size_t)gr * DIM
                                                   : Axt + (size_t)(gr - 400) * DIM;
                    v = *(const float4*)(rowp + kb + ak);
                } else {
                    v = *(const float4*)(A + (size_t)gr * DIM + kb + ak);
                    if (a_mode == 2) {      // fused prev-layer normalize + bias + relu
                        float inv = 1.f / (rsp[gr] + 1e-16f);
                        float4 bb = *(const float4*)&bp[kb + ak];
                        v.x = fmaxf(fmaf(v.x, inv, bb.x), 0.f);
                        v.y = fmaxf(fmaf(v.y, inv, bb.y), 0.f);
                        v.z = fmaxf(fmaf(v.z, inv, bb.z), 0.f);
                        v.w = fmaxf(fmaf(v.w, inv, bb.w), 0.f);
                    }
                }
            }
            Ast[ak + 0][ar] = v.x; Ast[ak + 1][ar] = v.y;
            Ast[ak + 2][ar] = v.z; Ast[ak + 3][ar] = v.w;
        }
        *(float4*)&Bs[bk][bn] = *(const float4*)&B[(size_t)(kb + bk) * DIM + col0 + bn];
        __syncthreads();
        #pragma unroll
        for (int kk = 0; kk < 16; kk++) {
            float4 a = *(const float4*)&Ast[kk][ty4];
            float4 b = *(const float4*)&Bs[kk][tx4];
            acc[0][0] += a.x*b.x; acc[0][1] += a.x*b.y; acc[0][2] += a.x*b.z; acc[0][3] += a.x*b.w;
            acc[1][0] += a.y*b.x; acc[1][1] += a.y*b.y; acc[1][2] += a.y*b.z; acc[1][3] += a.y*b.w;
            acc[2][0] += a.z*b.x; acc[2][1] += a.z*b.y; acc[2][2] += a.z*b.z; acc[2][3] += a.z*b.w;
            acc[3][0] += a.w*b.x; acc[3][1] += a.w*b.y; acc[3][2] += a.w*b.z; acc[3][3] += a.w*b.w;
        }
        __syncthreads();
    }

    // epilogue: atomic h partial + atomic logit partials (linear in h -> partials sum)
    float4 as4 = *(const float4*)&asrc[col0 + tx4];
    float4 ad4 = *(const float4*)&adst[col0 + tx4];
    #pragma unroll
    for (int i = 0; i < 4; i++) {
        int gr = row0 + ty4 + i;
        float sa = acc[i][0]*as4.x + acc[i][1]*as4.y + acc[i][2]*as4.z + acc[i][3]*as4.w;
        float sd = acc[i][0]*ad4.x + acc[i][1]*ad4.y + acc[i][2]*ad4.z + acc[i][3]*ad4.w;
        #pragma unroll
        for (int o = 8; o > 0; o >>= 1) {
            sa += __shfl_down(sa, o, 16);
            sd += __shfl_down(sd, o, 16);
        }
        if (gr < N_NODES) {
            float* hp = h + (size_t)gr * DIM + col0 + tx4;
            atomicAdd(hp + 0, acc[i][0]);
            atomicAdd(hp + 1, acc[i][1]);
            atomicAdd(hp + 2, acc[i][2]);
            atomicAdd(hp + 3, acc[i][3]);
            if ((t & 15) == 0) {
                atomicAdd(&als[gr], sa);
                atomicAdd(&ald[gr], sd);
            }
        }
    }
}

// =============== dense attention-matrix build from raw edge list ===============
// W[d][s] += exp(leaky(als[s]+ald[d])), rs[d] += same. W, rs pre-zeroed.
__global__ __launch_bounds__(256)
void k_build(const int* __restrict__ ei, const float* __restrict__ als,
             const float* __restrict__ ald, float* __restrict__ W,
             float* __restrict__ rs) {
    __shared__ float lrs[N_NODES];
    int t = threadIdx.x;
    for (int l = t; l < N_NODES; l += 256) lrs[l] = 0.f;
    __syncthreads();
    const int stride = gridDim.x * 256;
    for (int i = blockIdx.x * 256 + t; i < E_TOT; i += stride) {
        int s, d;
        if (i < E_RAW) { s = ei[i]; d = ei[E_RAW + i]; }
        else           { s = d = i - E_RAW; }
        float e = als[s] + ald[d];
        e = e > 0.f ? e : 0.2f * e;
        float ex = __expf(e);
        atomicAdd(&W[(size_t)d * WK + s], ex);
        atomicAdd(&lrs[d], ex);
    }
    __syncthreads();
    for (int l = t; l < N_NODES; l += 256)
        if (lrs[l] != 0.f) atomicAdd(&rs[l], lrs[l]);
}

// =============== agg GEMM (split-K z=6): oraw[d,c] += (W @ h)[d,c] partial ===============
// normalize/bias/activation applied by the consumer (k_feat mode 2 or k_final).
__global__ __launch_bounds__(256)
void k_agg(const float* __restrict__ W, const float* __restrict__ Bm,
           float* __restrict__ oraw) {
    __shared__ float Ast[16][68];
    __shared__ float Bs[16][64];
    int t = threadIdx.x;
    int tx4 = (t & 15) * 4, ty4 = (t >> 4) * 4;
    int row0 = blockIdx.y * 64, col0 = blockIdx.x * 64;
    int kbase = blockIdx.z * 112;
    int ar = t >> 2, ak = (t & 3) * 4;
    int bk = t >> 4, bn = (t & 15) * 4;
    float acc[4][4] = {};

    for (int kb = kbase; kb < kbase + 112; kb += 16) {
        {
            int gr = row0 + ar;
            float4 v = make_float4(0.f, 0.f, 0.f, 0.f);
            if (gr < N_NODES)
                v = *(const float4*)(W + (size_t)gr * WK + kb + ak);
            Ast[ak + 0][ar] = v.x; Ast[ak + 1][ar] = v.y;
            Ast[ak + 2][ar] = v.z; Ast[ak + 3][ar] = v.w;
        }
        *(float4*)&Bs[bk][bn] = *(const float4*)&Bm[(size_t)(kb + bk) * DIM + col0 + bn];
        __syncthreads();
        #pragma unroll
        for (int kk = 0; kk < 16; kk++) {
            float4 a = *(const float4*)&Ast[kk][ty4];
            float4 b = *(const float4*)&Bs[kk][tx4];
            acc[0][0] += a.x*b.x; acc[0][1] += a.x*b.y; acc[0][2] += a.x*b.z; acc[0][3] += a.x*b.w;
            acc[1][0] += a.y*b.x; acc[1][1] += a.y*b.y; acc[1][2] += a.y*b.z; acc[1][3] += a.y*b.w;
            acc[2][0] += a.z*b.x; acc[2][1] += a.z*b.y; acc[2][2] += a.z*b.z; acc[2][3] += a.z*b.w;
            acc[3][0] += a.w*b.x; acc[3][1] += a.w*b.y; acc[3][2] += a.w*b.z; acc[3][3] += a.w*b.w;
        }
        __syncthreads();
    }

    #pragma unroll
    for (int i = 0; i < 4; i++) {
        int gr = row0 + ty4 + i;
        if (gr < N_NODES) {
            float* op = oraw + (size_t)gr * DIM + col0 + tx4;
            atomicAdd(op + 0, acc[i][0]);
            atomicAdd(op + 1, acc[i][1]);
            atomicAdd(op + 2, acc[i][2]);
            atomicAdd(op + 3, acc[i][3]);
        }
    }
}

// =============== final: act(o2raw) viewed as (512,650) @ fc_w + fc_b -> sigmoid ===============
__global__ void k_final(const float* __restrict__ oraw, const float* __restrict__ rs,
                        const float* __restrict__ bias,
                        const float* __restrict__ fcw, const float* __restrict__ fcb,
                        float* __restrict__ out) {
    int b = blockIdx.x * 4 + (threadIdx.x >> 6);
    int lane = threadIdx.x & 63;
    if (b >= 512) return;
    float s = 0.f;
    for (int i = lane; i < N_NODES; i += 64) {
        int j = b * N_NODES + i;
        int r = j >> 9, c = j & 511;           // o2 storage is (650, 512) row-major
        float v = fmaf(oraw[j], 1.f / (rs[r] + 1e-16f), bias[c]);
        v = v > 0.f ? v : 0.01f * v;
        s += v * fcw[i];
    }
    #pragma unroll
    for (int o = 32; o > 0; o >>= 1) s += __shfl_down(s, o);
    if (lane == 0) out[b] = 1.f / (1.f + expf(-(s + fcb[0])));
}

extern "C" void kernel_launch(void* const* d_in, const int* in_sizes, int n_in,
                              void* d_out, int out_size, void* d_ws, size_t ws_size,
                              hipStream_t stream) {
    const float* x_s   = (const float*)d_in[0];
    const float* x_t   = (const float*)d_in[1];
    const int*   ei    = (const int*)d_in[2];
    const float* W1    = (const float*)d_in[5];
    const float* asrc1 = (const float*)d_in[6];
    const float* adst1 = (const float*)d_in[7];
    const float* b1    = (const float*)d_in[8];
    const float* W4    = (const float*)d_in[9];
    const float* asrc4 = (const float*)d_in[10];
    const float* adst4 = (const float*)d_in[11];
    const float* b4    = (const float*)d_in[12];
    const float* fcw   = (const float*)d_in[13];
    const float* fcb   = (const float*)d_in[14];
    float* out = (float*)d_out;

    // workspace (all atomic-accumulated buffers zeroed by ONE upfront memset):
    // [ h1 (672x512) | h2 (672x512) | o1raw | o2raw | als1 ald1 als2 ald2 rs1 rs2 | W1d | W2d ]
    const size_t S = (size_t)N_NODES * DIM;          // 332800
    float* ws    = (float*)d_ws;
    float* h1    = ws;                               // WK*DIM = 344064 (pad rows zero)
    float* h2    = h1 + (size_t)WK * DIM;            // 344064
    float* o1raw = h2 + (size_t)WK * DIM;            // 332800
    float* o2raw = o1raw + S;                        // 332800
    float* als1  = o2raw + S;                        // 650
    float* ald1  = als1 + N_NODES;
    float* als2  = ald1 + N_NODES;
    float* ald2  = als2 + N_NODES;
    float* rs1   = ald2 + N_NODES;
    float* rs2   = rs1 + N_NODES;
    float* W1d   = rs2 + N_NODES;                    // 650*672
    float* W2d   = W1d + (size_t)N_NODES * WK;       // 650*672

    size_t zbytes = (size_t)(2 * WK * DIM            // h1, h2
                           + 2 * S                   // o1raw, o2raw
                           + 6 * N_NODES             // logits + rowsums
                           + 2 * N_NODES * WK)       // W1d, W2d
                    * sizeof(float);
    hipMemsetAsync(ws, 0, zbytes, stream);

    dim3 gF(DIM / 64, (N_NODES + 63) / 64, 8);       // 8 x 11 x 8 = 704 blocks
    dim3 gA(DIM / 64, (N_NODES + 63) / 64, 6);       // 8 x 11 x 6 = 528 blocks

    // ---- layer 1 ----
    k_feat<<<gF, 256, 0, stream>>>(x_s, x_t, W1, asrc1, adst1, nullptr, nullptr,
                                   h1, als1, ald1, 1);
    k_build<<<128, 256, 0, stream>>>(ei, als1, ald1, W1d, rs1);
    k_agg<<<gA, 256, 0, stream>>>(W1d, h1, o1raw);

    // ---- layer 2 (normalize/bias/relu of layer 1 fused into A-staging) ----
    k_feat<<<gF, 256, 0, stream>>>(o1raw, nullptr, W4, asrc4, adst4, rs1, b1,
                                   h2, als2, ald2, 2);
    k_build<<<128, 256, 0, stream>>>(ei, als2, ald2, W2d, rs2);
    k_agg<<<gA, 256, 0, stream>>>(W2d, h2, o2raw);

    // ---- final (normalize/bias/leaky of layer 2 fused into load) ----
    k_final<<<128, 256, 0, stream>>>(o2raw, rs2, b4, fcw, fcb, out);
}